// Round 14
// baseline (254.411 us; speedup 1.0000x reference)
//
#include <hip/hip_runtime.h>
#include <hip/hip_bf16.h>

using bf16 = __hip_bfloat16;
typedef __attribute__((ext_vector_type(8))) __bf16 bf16x8;
typedef __attribute__((ext_vector_type(4))) short s16x4;
typedef __attribute__((ext_vector_type(4))) float f32x4;

#define B_   4
#define T_   2048
#define D_   1024
#define H_   16
#define HD_  64
#define BH_  (B_ * H_)
#define BT_  (B_ * T_)

// Q pre-scale: 1/sqrt(64) * log2(e)  -> softmax computed with exp2
#define QSCALE 0.18033688011112042f

// async global->LDS DMA, 16B per lane; LDS dest is wave-uniform base + lane*16
__device__ __forceinline__ void gld_lds16(const void* g, void* l) {
    __builtin_amdgcn_global_load_lds(
        (const __attribute__((address_space(1))) unsigned int*)g,
        (__attribute__((address_space(3))) unsigned int*)l,
        16, 0, 0);
}

// 16x16x16 bf16 MFMA (B-frag k = (lane>>4)*4 + j == QK^T C-frag layout).
__device__ __forceinline__ f32x4 mfma16(s16x4 a, s16x4 b, f32x4 c) {
#if defined(__HIP_DEVICE_COMPILE__)
  #if __has_builtin(__builtin_amdgcn_mfma_f32_16x16x16bf16_1k)
    return __builtin_amdgcn_mfma_f32_16x16x16bf16_1k(a, b, c, 0, 0, 0);
  #else
    f32x4 d;
    asm volatile("v_mfma_f32_16x16x16_bf16 %0, %1, %2, %3\n\ts_nop 7\n\ts_nop 7"
                 : "=v"(d) : "v"(a), "v"(b), "v"(c));
    return d;
  #endif
#else
    (void)a; (void)b;
    return c;
#endif
}

__device__ __forceinline__ unsigned bfbits(float x) {
    return (unsigned)__builtin_bit_cast(unsigned short, __float2bfloat16(x));
}

// ---------------------------------------------------------------- cast fp32 -> bf16
__global__ void cast_kernel(const float* __restrict__ in, bf16* __restrict__ out, int n4) {
    int i = blockIdx.x * 256 + threadIdx.x;
    if (i >= n4) return;
    float4 v = reinterpret_cast<const float4*>(in)[i];
    union { bf16 h[4]; uint2 u; } tmp;
    tmp.h[0] = __float2bfloat16(v.x);
    tmp.h[1] = __float2bfloat16(v.y);
    tmp.h[2] = __float2bfloat16(v.z);
    tmp.h[3] = __float2bfloat16(v.w);
    reinterpret_cast<uint2*>(out)[i] = tmp.u;
}

// ---------------------------------------------------------------- W[K][N] fp32 -> Wt[N][K] bf16
__global__ void transpose_cast(const float* __restrict__ W, bf16* __restrict__ Wt,
                               int K, int N) {
    __shared__ float tile[32][33];
    int nb = blockIdx.x * 32, kb = blockIdx.y * 32;
    int tx = threadIdx.x, ty = threadIdx.y;   // 32 x 8
    #pragma unroll
    for (int i = 0; i < 32; i += 8)
        tile[ty + i][tx] = W[(size_t)(kb + ty + i) * N + nb + tx];
    __syncthreads();
    #pragma unroll
    for (int i = 0; i < 32; i += 8)
        Wt[(size_t)(nb + ty + i) * K + kb + tx] = __float2bfloat16(tile[tx][ty + i]);
}

// ---------------------------------------------------------------- GEMM  C = A @ Bt^T (+bias)
// 128x128 tile, K=1024, BK=32. A-operand DIRECT from global into registers
// (ping-pong reg sets, prefetched 1 phase ahead; waves 0/1 and 2/3 issue identical
// A addresses -> L1 dedup). LDS holds B ONLY: ring-4 x 8KB, DMA-staged, XOR-swizzled
// (0-conflict verified). Per-phase LDS traffic halves vs A+B staging (48->24 KB).
// FIFO: issue A(t+1)[4] then DMA B(t+3)[2]; end-of-phase vmcnt(2) leaves only B(t+3).
// MODE 0: QKV scatter. MODE 1: fp32 + bias.
template <int MODE>
__global__ __launch_bounds__(256)
void gemm_bt(const bf16* __restrict__ A, const bf16* __restrict__ Bt,
             const float* __restrict__ bias,
             bf16* __restrict__ Qo, bf16* __restrict__ Ko, bf16* __restrict__ Vo,
             float* __restrict__ Fo) {
    constexpr int K = 1024;
    const int bm = blockIdx.x * 128;
    const int bn = blockIdx.y * 128;
    const int tid  = threadIdx.x;
    const int wid  = tid >> 6;
    const int lane = tid & 63;
    const int wr = (wid >> 1) * 64;
    const int wc = (wid & 1) * 64;
    const int ln_g = lane >> 4;    // 0..3
    const int ln_c = lane & 15;    // 0..15

    __shared__ bf16 smB[4][128][32];     // ring-4 B slots, 32 KB total

    f32x4 acc[4][4] = {};

    const int g_row0 = wid * 32 + (lane >> 2);
    const int g_chk  = ((lane & 3) ^ ((lane >> 3) & 3)) * 8;
    const int l_row0 = wid * 32;
    const int colx = (ln_g * 16) ^ (((ln_c >> 1) & 3) << 4);

    const bf16* Arow = A + (size_t)(bm + wr + ln_c) * K + ln_g * 8;

#define LOADA(R_, T_) {                                                                  \
    _Pragma("unroll")                                                                    \
    for (int m = 0; m < 4; ++m)                                                          \
        R_[m] = *reinterpret_cast<const bf16x8*>(&Arow[(size_t)m * 16 * K + (T_) * 32]); }

#define STAGEB(S_, T_) {                                                                 \
    gld_lds16(&Bt[(size_t)(bn + g_row0)      * K + (T_) * 32 + g_chk], &smB[S_][l_row0][0]);      \
    gld_lds16(&Bt[(size_t)(bn + g_row0 + 16) * K + (T_) * 32 + g_chk], &smB[S_][l_row0 + 16][0]); }

#define COMPUTE(S_, AF_) {                                                               \
    bf16x8 bfr[4];                                                                       \
    _Pragma("unroll")                                                                    \
    for (int n = 0; n < 4; ++n)                                                          \
        bfr[n] = *reinterpret_cast<const bf16x8*>(                                       \
            (const char*)&smB[S_][wc + n * 16 + ln_c][0] + colx);                        \
    _Pragma("unroll")                                                                    \
    for (int m = 0; m < 4; ++m)                                                          \
        _Pragma("unroll")                                                                \
        for (int n = 0; n < 4; ++n)                                                      \
            acc[m][n] = __builtin_amdgcn_mfma_f32_16x16x32_bf16(AF_[m], bfr[n],          \
                                                                 acc[m][n], 0, 0, 0); }

#define WAITV(N_) { asm volatile("s_waitcnt vmcnt(" #N_ ") lgkmcnt(0)" ::: "memory");    \
                    __builtin_amdgcn_s_barrier();                                        \
                    __builtin_amdgcn_sched_barrier(0); }

    bf16x8 afA[4], afB[4];

    // prologue: B tiles 0,1,2 into slots 0,1,2; A tile 0 into afA
    STAGEB(0, 0);
    STAGEB(1, 1);
    STAGEB(2, 2);
    LOADA(afA, 0);
    WAITV(0);

    // phases 0..27 (7 x 4, ping-pong afA/afB, slot = t&3); guards all true
    #pragma unroll 1
    for (int i = 0; i < 7; ++i) {
        const int t0 = i * 4;
        LOADA(afB, t0 + 1); STAGEB((t0 + 3) & 3, t0 + 3); COMPUTE((t0 + 0) & 3, afA); WAITV(2);
        LOADA(afA, t0 + 2); STAGEB((t0 + 4) & 3, t0 + 4); COMPUTE((t0 + 1) & 3, afB); WAITV(2);
        LOADA(afB, t0 + 3); STAGEB((t0 + 5) & 3, t0 + 5); COMPUTE((t0 + 2) & 3, afA); WAITV(2);
        LOADA(afA, t0 + 4); STAGEB((t0 + 6) & 3, t0 + 6); COMPUTE((t0 + 3) & 3, afB); WAITV(2);
    }
    // tail: t=28..31 (after loop: afA holds tile 28; B staged through tile 30)
    LOADA(afB, 29); STAGEB(3, 31); COMPUTE(0, afA); WAITV(2);
    LOADA(afA, 30);                COMPUTE(1, afB); WAITV(0);
    LOADA(afB, 31);                COMPUTE(2, afA); WAITV(0);
                                   COMPUTE(3, afB);

#undef LOADA
#undef STAGEB
#undef COMPUTE
#undef WAITV

    #pragma unroll
    for (int m = 0; m < 4; ++m) {
        #pragma unroll
        for (int n = 0; n < 4; ++n) {
            const int col = bn + wc + n * 16 + ln_c;
            const float bcol = bias[col];
            #pragma unroll
            for (int j = 0; j < 4; ++j) {
                const int row = bm + wr + m * 16 + ln_g * 4 + j;
                float v = acc[m][n][j] + bcol;
                if (MODE == 0) {
                    const int part = col >> 10;       // 0=q 1=k 2=v
                    const int cc = col & 1023;
                    const int h = cc >> 6, d = cc & 63;
                    const int b = row >> 11, t = row & 2047;
                    const int bh = b * H_ + h;
                    if (part == 0)
                        Qo[((size_t)bh * T_ + t) * HD_ + d] = __float2bfloat16(v * QSCALE);
                    else if (part == 1)
                        Ko[((size_t)bh * T_ + t) * HD_ + d] = __float2bfloat16(v);
                    else
                        Vo[((size_t)bh * HD_ + d) * T_ + t] = __float2bfloat16(v);
                } else {
                    Fo[(size_t)row * D_ + col] = v;
                }
            }
        }
    }
}

// ---------------------------------------------------------------- causal flash attention v4b
// Swapped-operand QK^T (S^T in registers, q lane-local) + register-direct PV via
// mfma 16x16x16 (P packed with scalar bit-ops -> no scratch) + shuffle-free common
// path. LDS 18.4 KB; launch_bounds(256,4) -> 128-VGPR cap (fits live set, no spill).
// Q,K: [bh][t][64] bf16 (Q pre-scaled by QSCALE). Vt: [bh][64][t] bf16.
__global__ __launch_bounds__(256, 4)
void attn_kernel(const bf16* __restrict__ Q, const bf16* __restrict__ K,
                 const bf16* __restrict__ Vt, bf16* __restrict__ ctx) {
    const int bh = blockIdx.x & 63;
    const int qt = 31 - (blockIdx.x >> 6);   // longest blocks dispatched first
    const int tid  = threadIdx.x;
    const int wave = tid >> 6;
    const int lane = tid & 63;
    const int ln_g = lane >> 4;      // 0..3
    const int ln_c = lane & 15;      // 0..15

    const bf16* Qp = Q  + (size_t)bh * T_ * HD_;
    const bf16* Kp = K  + (size_t)bh * T_ * HD_;
    const bf16* Vp = Vt + (size_t)bh * HD_ * T_;

    __shared__ bf16 Ks[64][72];
    __shared__ bf16 Vs[64][72];

    const int srow = tid >> 3;       // 0..31
    const int sc8  = (tid & 7) * 8;  // 0..56

    const int b = bh >> 4, h = bh & 15;

    const int qbase = qt * 64;
    const int qglob = qbase + wave * 16 + ln_c;    // this lane's q row

    const bf16x8 qf0 = *reinterpret_cast<const bf16x8*>(&Qp[(size_t)qglob * HD_ + ln_g * 8]);
    const bf16x8 qf1 = *reinterpret_cast<const bf16x8*>(&Qp[(size_t)qglob * HD_ + 32 + ln_g * 8]);

    f32x4 o[4] = {};                // o[dt][j] = O^T[dt*16 + ln_g*4 + j][q=ln_c]
    float m = -INFINITY, l = 0.f;   // per-lane partial l (this lane's k subset)

    const int nk = qt + 1;          // 64-wide kv tiles

    int4 kr0, kr1, vr0, vr1;
    kr0 = *reinterpret_cast<const int4*>(&Kp[(size_t)srow * HD_ + sc8]);
    kr1 = *reinterpret_cast<const int4*>(&Kp[(size_t)(srow + 32) * HD_ + sc8]);
    vr0 = *reinterpret_cast<const int4*>(&Vp[(size_t)srow * T_ + sc8]);
    vr1 = *reinterpret_cast<const int4*>(&Vp[(size_t)(srow + 32) * T_ + sc8]);
    *reinterpret_cast<int4*>(&Ks[srow][sc8])      = kr0;
    *reinterpret_cast<int4*>(&Ks[srow + 32][sc8]) = kr1;
    *reinterpret_cast<int4*>(&Vs[srow][sc8])      = vr0;
    *reinterpret_cast<int4*>(&Vs[srow + 32][sc8]) = vr1;
    __syncthreads();

    for (int it = 0; it < nk; ++it) {
        const int kb = it * 64;
        const bool notlast = (it + 1 < nk);
        if (notlast) {   // async-stage split: issue next tile's loads now
            const int kn = kb + 64;
            kr0 = *reinterpret_cast<const int4*>(&Kp[(size_t)(kn + srow) * HD_ + sc8]);
            kr1 = *reinterpret_cast<const int4*>(&Kp[(size_t)(kn + srow + 32) * HD_ + sc8]);
            vr0 = *reinterpret_cast<const int4*>(&Vp[(size_t)srow * T_ + kn + sc8]);
            vr1 = *reinterpret_cast<const int4*>(&Vp[(size_t)(srow + 32) * T_ + kn + sc8]);
        }

        // ---- S^T = K Q^T : st[kk][j] <-> k = kb + kk*16 + ln_g*4 + j, q = qglob
        f32x4 st[4];
        __builtin_amdgcn_s_setprio(1);
        #pragma unroll
        for (int kk = 0; kk < 4; ++kk) {
            bf16x8 kfa = *reinterpret_cast<const bf16x8*>(&Ks[kk * 16 + ln_c][ln_g * 8]);
            bf16x8 kfb = *reinterpret_cast<const bf16x8*>(&Ks[kk * 16 + ln_c][32 + ln_g * 8]);
            f32x4 z = {0.f, 0.f, 0.f, 0.f};
            z = __builtin_amdgcn_mfma_f32_16x16x32_bf16(kfa, qf0, z, 0, 0, 0);
            z = __builtin_amdgcn_mfma_f32_16x16x32_bf16(kfb, qf1, z, 0, 0, 0);
            st[kk] = z;
        }
        __builtin_amdgcn_s_setprio(0);

        if (!notlast) {   // diagonal tile: causal mask
            #pragma unroll
            for (int kk = 0; kk < 4; ++kk)
                #pragma unroll
                for (int j = 0; j < 4; ++j)
                    if (kb + kk * 16 + ln_g * 4 + j > qglob) st[kk][j] = -INFINITY;
        }

        // ---- per-lane local max; shuffle-free defer check (rescale is rare)
        float mx = -INFINITY;
        #pragma unroll
        for (int kk = 0; kk < 4; ++kk)
            #pragma unroll
            for (int j = 0; j < 4; ++j)
                mx = fmaxf(mx, st[kk][j]);
        if (!__all(mx - m <= 8.f)) {
            float r = fmaxf(mx, __shfl_xor(mx, 16));
            r = fmaxf(r, __shfl_xor(r, 32));          // row max (uniform per q-row)
            const float mnew = fmaxf(m, r);
            const float alpha = exp2f(m - mnew);
            l *= alpha;
            #pragma unroll
            for (int dt = 0; dt < 4; ++dt)
                #pragma unroll
                for (int j = 0; j < 4; ++j)
                    o[dt][j] *= alpha;
            m = mnew;
        }

        // ---- P = exp2(S - m); pack to s16x4 via scalar bit-ops (stays in VGPRs);
        //      PV: O^T += V^T P^T via mfma 16x16x16, P direct from registers.
        #pragma unroll
        for (int kk = 0; kk < 4; ++kk) {
            float p0 = exp2f(st[kk][0] - m);
            float p1 = exp2f(st[kk][1] - m);
            float p2 = exp2f(st[kk][2] - m);
            float p3 = exp2f(st[kk][3] - m);
            l += (p0 + p1) + (p2 + p3);
            uint2 pw;
            pw.x = bfbits(p0) | (bfbits(p1) << 16);
            pw.y = bfbits(p2) | (bfbits(p3) << 16);
            const s16x4 ps = __builtin_bit_cast(s16x4, pw);
            __builtin_amdgcn_s_setprio(1);
            #pragma unroll
            for (int dt = 0; dt < 4; ++dt) {
                s16x4 vf = *reinterpret_cast<const s16x4*>(
                    &Vs[dt * 16 + ln_c][kk * 16 + ln_g * 4]);
                o[dt] = mfma16(vf, ps, o[dt]);
            }
            __builtin_amdgcn_s_setprio(0);
        }

        if (notlast) {
            __syncthreads();
            *reinterpret_cast<int4*>(&Ks[srow][sc8])      = kr0;
            *reinterpret_cast<int4*>(&Ks[srow + 32][sc8]) = kr1;
            *reinterpret_cast<int4*>(&Vs[srow][sc8])      = vr0;
            *reinterpret_cast<int4*>(&Vs[srow + 32][sc8]) = vr1;
            __syncthreads();
        }
    }

    // ---- epilogue: reduce l across the 4 ln_g groups (once), then write O^T
    l += __shfl_xor(l, 16);
    l += __shfl_xor(l, 32);
    const float inv = 1.0f / l;
    bf16* dst = ctx + ((size_t)(b * T_ + qglob)) * D_ + h * HD_;
    #pragma unroll
    for (int dt = 0; dt < 4; ++dt) {
        union { bf16 hh[4]; uint2 u; } ok;
        #pragma unroll
        for (int j = 0; j < 4; ++j)
            ok.hh[j] = __float2bfloat16(o[dt][j] * inv);
        *reinterpret_cast<uint2*>(&dst[dt * 16 + ln_g * 4]) = ok.u;
    }
}

// ---------------------------------------------------------------- launch
extern "C" void kernel_launch(void* const* d_in, const int* in_sizes, int n_in,
                              void* d_out, int out_size, void* d_ws, size_t ws_size,
                              hipStream_t stream) {
    const float* x      = (const float*)d_in[0];
    const float* W_attn = (const float*)d_in[1];
    const float* b_attn = (const float*)d_in[2];
    const float* W_proj = (const float*)d_in[3];
    const float* b_proj = (const float*)d_in[4];
    float* out = (float*)d_out;

    char* ws = (char*)d_ws;
    bf16* xh  = (bf16*)ws;  ws += (size_t)BT_ * D_ * 2;
    bf16* WaT = (bf16*)ws;  ws += (size_t)3 * D_ * D_ * 2;
    bf16* WpT = (bf16*)ws;  ws += (size_t)D_ * D_ * 2;
    bf16* Qb  = (bf16*)ws;  ws += (size_t)BH_ * T_ * HD_ * 2;
    bf16* Kb  = (bf16*)ws;  ws += (size_t)BH_ * T_ * HD_ * 2;
    bf16* Vb  = (bf16*)ws;  ws += (size_t)BH_ * T_ * HD_ * 2;
    bf16* ctx = (bf16*)ws;  ws += (size_t)BT_ * D_ * 2;

    cast_kernel<<<(BT_ * D_ / 4 + 255) / 256, 256, 0, stream>>>(x, xh, BT_ * D_ / 4);
    transpose_cast<<<dim3(3 * D_ / 32, D_ / 32), dim3(32, 8), 0, stream>>>(W_attn, WaT, D_, 3 * D_);
    transpose_cast<<<dim3(D_ / 32, D_ / 32), dim3(32, 8), 0, stream>>>(W_proj, WpT, D_, D_);

    gemm_bt<0><<<dim3(BT_ / 128, 3 * D_ / 128), 256, 0, stream>>>(
        xh, WaT, b_attn, Qb, Kb, Vb, nullptr);

    attn_kernel<<<dim3(BH_ * 32), 256, 0, stream>>>(Qb, Kb, Vb, ctx);

    gemm_bt<1><<<dim3(BT_ / 128, D_ / 128), 256, 0, stream>>>(
        ctx, WpT, b_proj, nullptr, nullptr, nullptr, out);
}

// Round 16
// 193.412 us; speedup vs baseline: 1.3154x; 1.3154x over previous
//
#include <hip/hip_runtime.h>
#include <hip/hip_bf16.h>

using bf16 = __hip_bfloat16;
typedef __attribute__((ext_vector_type(8))) __bf16 bf16x8;
typedef __attribute__((ext_vector_type(4))) short s16x4;
typedef __attribute__((ext_vector_type(4))) float f32x4;

#define B_   4
#define T_   2048
#define D_   1024
#define H_   16
#define HD_  64
#define BH_  (B_ * H_)
#define BT_  (B_ * T_)

// Q pre-scale: 1/sqrt(64) * log2(e)  -> softmax computed with exp2
#define QSCALE 0.18033688011112042f

// async global->LDS DMA, 16B per lane; LDS dest is wave-uniform base + lane*16
__device__ __forceinline__ void gld_lds16(const void* g, void* l) {
    __builtin_amdgcn_global_load_lds(
        (const __attribute__((address_space(1))) unsigned int*)g,
        (__attribute__((address_space(3))) unsigned int*)l,
        16, 0, 0);
}

// 16x16x16 bf16 MFMA (B-frag k = (lane>>4)*4 + j == QK^T C-frag layout).
__device__ __forceinline__ f32x4 mfma16(s16x4 a, s16x4 b, f32x4 c) {
#if defined(__HIP_DEVICE_COMPILE__)
  #if __has_builtin(__builtin_amdgcn_mfma_f32_16x16x16bf16_1k)
    return __builtin_amdgcn_mfma_f32_16x16x16bf16_1k(a, b, c, 0, 0, 0);
  #else
    f32x4 d;
    asm volatile("v_mfma_f32_16x16x16_bf16 %0, %1, %2, %3\n\ts_nop 7\n\ts_nop 7"
                 : "=v"(d) : "v"(a), "v"(b), "v"(c));
    return d;
  #endif
#else
    (void)a; (void)b;
    return c;
#endif
}

__device__ __forceinline__ unsigned bfbits(float x) {
    return (unsigned)__builtin_bit_cast(unsigned short, __float2bfloat16(x));
}

// ---------------------------------------------------------------- cast fp32 -> bf16
__global__ void cast_kernel(const float* __restrict__ in, bf16* __restrict__ out, int n4) {
    int i = blockIdx.x * 256 + threadIdx.x;
    if (i >= n4) return;
    float4 v = reinterpret_cast<const float4*>(in)[i];
    union { bf16 h[4]; uint2 u; } tmp;
    tmp.h[0] = __float2bfloat16(v.x);
    tmp.h[1] = __float2bfloat16(v.y);
    tmp.h[2] = __float2bfloat16(v.z);
    tmp.h[3] = __float2bfloat16(v.w);
    reinterpret_cast<uint2*>(out)[i] = tmp.u;
}

// ---------------------------------------------------------------- W[K][N] fp32 -> Wt[N][K] bf16
__global__ void transpose_cast(const float* __restrict__ W, bf16* __restrict__ Wt,
                               int K, int N) {
    __shared__ float tile[32][33];
    int nb = blockIdx.x * 32, kb = blockIdx.y * 32;
    int tx = threadIdx.x, ty = threadIdx.y;   // 32 x 8
    #pragma unroll
    for (int i = 0; i < 32; i += 8)
        tile[ty + i][tx] = W[(size_t)(kb + ty + i) * N + nb + tx];
    __syncthreads();
    #pragma unroll
    for (int i = 0; i < 32; i += 8)
        Wt[(size_t)(nb + ty + i) * K + kb + tx] = __float2bfloat16(tile[tx][ty + i]);
}

// ---------------------------------------------------------------- QKV GEMM, 256x256 tile
// K=1024, BK=32, 512 threads / 8 waves (2 wave-rows x 4 wave-cols), per-wave output
// 128x64 (acc[8][4]) -> LDS traffic 32 KB/MFLOP (vs 48 at 128^2). Ring-3 x 32 KB
// dynamic LDS, R13's verified counted-vmcnt schedule (4 DMA calls/stage, vmcnt(4)),
// same XOR swizzle (0-conflict verified). Epilogue scatters Q*QSCALE, K, V^T.
__global__ __launch_bounds__(512, 2)
void gemm_qkv256(const bf16* __restrict__ A, const bf16* __restrict__ Bt,
                 const float* __restrict__ bias,
                 bf16* __restrict__ Qo, bf16* __restrict__ Ko, bf16* __restrict__ Vo) {
    constexpr int K = 1024;
    extern __shared__ char smem[];       // 3 slots x (A 16KB + B 16KB) = 96 KB
    const int bm = blockIdx.x * 256;
    const int bn = blockIdx.y * 256;
    const int tid  = threadIdx.x;
    const int wid  = tid >> 6;
    const int lane = tid & 63;
    const int wr = (wid >> 2) * 128;     // 0 / 128
    const int wc = (wid & 3) * 64;       // 0..192
    const int ln_g = lane >> 4;          // 0..3
    const int ln_c = lane & 15;          // 0..15

    f32x4 acc[8][4] = {};

    // staging: per call 128 rows (4 lanes/row); wave w covers rows w*16..w*16+15
    const int s_row = wid * 16 + (lane >> 2);               // row within 128-half
    const int g_chk = ((lane & 3) ^ ((lane >> 3) & 3)) * 8; // pre-swizzled elem off
    const int l_off = wid * 1024;                           // wave byte base in half

    // read-side: swizzle folds to constant byte offset
    const int colx = (ln_g * 16) ^ (((ln_c >> 1) & 3) << 4);
    const char* aB = smem + (wr + ln_c) * 64 + colx;
    const char* bB = smem + 16384 + (wc + ln_c) * 64 + colx;

#define STAGE(S_, T_) {                                                                   \
    gld_lds16(&A [(size_t)(bm + s_row)       * K + (T_) * 32 + g_chk], smem + (S_)*32768 + l_off);          \
    gld_lds16(&A [(size_t)(bm + 128 + s_row) * K + (T_) * 32 + g_chk], smem + (S_)*32768 + 8192 + l_off);   \
    gld_lds16(&Bt[(size_t)(bn + s_row)       * K + (T_) * 32 + g_chk], smem + (S_)*32768 + 16384 + l_off);  \
    gld_lds16(&Bt[(size_t)(bn + 128 + s_row) * K + (T_) * 32 + g_chk], smem + (S_)*32768 + 24576 + l_off); }

#define COMPUTE(S_) {                                                                    \
    bf16x8 af[8], bfr[4];                                                                \
    _Pragma("unroll")                                                                    \
    for (int m = 0; m < 8; ++m)                                                          \
        af[m] = *reinterpret_cast<const bf16x8*>(aB + (S_) * 32768 + m * 1024);          \
    _Pragma("unroll")                                                                    \
    for (int n = 0; n < 4; ++n)                                                          \
        bfr[n] = *reinterpret_cast<const bf16x8*>(bB + (S_) * 32768 + n * 1024);         \
    _Pragma("unroll")                                                                    \
    for (int m = 0; m < 8; ++m)                                                          \
        _Pragma("unroll")                                                                \
        for (int n = 0; n < 4; ++n)                                                      \
            acc[m][n] = __builtin_amdgcn_mfma_f32_16x16x32_bf16(af[m], bfr[n],           \
                                                                 acc[m][n], 0, 0, 0); }

#define WAITV4 { asm volatile("s_waitcnt vmcnt(4) lgkmcnt(0)" ::: "memory");             \
                 __builtin_amdgcn_s_barrier();                                           \
                 __builtin_amdgcn_sched_barrier(0); }
#define WAITV0 { asm volatile("s_waitcnt vmcnt(0) lgkmcnt(0)" ::: "memory");             \
                 __builtin_amdgcn_s_barrier();                                           \
                 __builtin_amdgcn_sched_barrier(0); }

    // prologue: stage tiles 0,1 into slots 0,1
    STAGE(0, 0);
    STAGE(1, 1);

    // 30 tiles in 10 triples; per triple i: stage tiles 3i+2,3i+3,3i+4 (slot t%3),
    // compute tiles 3i,3i+1,3i+2. (R13-verified induction; 4 calls/stage.)
    #pragma unroll 1
    for (int i = 0; i < 10; ++i) {
        const int t0 = i * 3;
        WAITV4; STAGE(2, t0 + 2); COMPUTE(0);
        WAITV4; STAGE(0, t0 + 3); COMPUTE(1);
        WAITV4; STAGE(1, t0 + 4); COMPUTE(2);
    }
    WAITV4; COMPUTE(0);   // tile 30 (tile 31's stage in flight)
    WAITV0; COMPUTE(1);   // tile 31

#undef STAGE
#undef COMPUTE
#undef WAITV4
#undef WAITV0

    #pragma unroll
    for (int m = 0; m < 8; ++m) {
        #pragma unroll
        for (int n = 0; n < 4; ++n) {
            const int col = bn + wc + n * 16 + ln_c;
            const float bcol = bias[col];
            #pragma unroll
            for (int j = 0; j < 4; ++j) {
                const int row = bm + wr + m * 16 + ln_g * 4 + j;
                float v = acc[m][n][j] + bcol;
                const int part = col >> 10;       // 0=q 1=k 2=v
                const int cc = col & 1023;
                const int h = cc >> 6, d = cc & 63;
                const int b = row >> 11, t = row & 2047;
                const int bh = b * H_ + h;
                if (part == 0)
                    Qo[((size_t)bh * T_ + t) * HD_ + d] = __float2bfloat16(v * QSCALE);
                else if (part == 1)
                    Ko[((size_t)bh * T_ + t) * HD_ + d] = __float2bfloat16(v);
                else
                    Vo[((size_t)bh * HD_ + d) * T_ + t] = __float2bfloat16(v);
            }
        }
    }
}

// ---------------------------------------------------------------- proj GEMM (R13 128^2 ring-3)
__global__ __launch_bounds__(256)
void gemm_proj(const bf16* __restrict__ A, const bf16* __restrict__ Bt,
               const float* __restrict__ bias, float* __restrict__ Fo) {
    constexpr int K = 1024;
    const int bm = blockIdx.x * 128;
    const int bn = blockIdx.y * 128;
    const int tid  = threadIdx.x;
    const int wid  = tid >> 6;
    const int lane = tid & 63;
    const int wr = (wid >> 1) * 64;
    const int wc = (wid & 1) * 64;
    const int ln_g = lane >> 4;
    const int ln_c = lane & 15;

    __shared__ bf16 sm[3][2][128][32];

    f32x4 acc[4][4] = {};

    const int g_row0 = wid * 32 + (lane >> 2);
    const int g_chk  = ((lane & 3) ^ ((lane >> 3) & 3)) * 8;
    const int l_row0 = wid * 32;
    const int colx = (ln_g * 16) ^ (((ln_c >> 1) & 3) << 4);

#define STAGE(S_, T_) {                                                               \
    gld_lds16(&A [(size_t)(bm + g_row0)      * K + (T_) * 32 + g_chk], &sm[S_][0][l_row0][0]);      \
    gld_lds16(&A [(size_t)(bm + g_row0 + 16) * K + (T_) * 32 + g_chk], &sm[S_][0][l_row0 + 16][0]); \
    gld_lds16(&Bt[(size_t)(bn + g_row0)      * K + (T_) * 32 + g_chk], &sm[S_][1][l_row0][0]);      \
    gld_lds16(&Bt[(size_t)(bn + g_row0 + 16) * K + (T_) * 32 + g_chk], &sm[S_][1][l_row0 + 16][0]); }

#define COMPUTE(S_) {                                                                    \
    bf16x8 af[4], bfr[4];                                                                \
    _Pragma("unroll")                                                                    \
    for (int m = 0; m < 4; ++m)                                                          \
        af[m] = *reinterpret_cast<const bf16x8*>(                                        \
            (const char*)&sm[S_][0][wr + m * 16 + ln_c][0] + colx);                      \
    _Pragma("unroll")                                                                    \
    for (int n = 0; n < 4; ++n)                                                          \
        bfr[n] = *reinterpret_cast<const bf16x8*>(                                       \
            (const char*)&sm[S_][1][wc + n * 16 + ln_c][0] + colx);                      \
    _Pragma("unroll")                                                                    \
    for (int m = 0; m < 4; ++m)                                                          \
        _Pragma("unroll")                                                                \
        for (int n = 0; n < 4; ++n)                                                      \
            acc[m][n] = __builtin_amdgcn_mfma_f32_16x16x32_bf16(af[m], bfr[n],           \
                                                                 acc[m][n], 0, 0, 0); }

#define WAITV4 { asm volatile("s_waitcnt vmcnt(4) lgkmcnt(0)" ::: "memory");             \
                 __builtin_amdgcn_s_barrier();                                           \
                 __builtin_amdgcn_sched_barrier(0); }
#define WAITV0 { asm volatile("s_waitcnt vmcnt(0) lgkmcnt(0)" ::: "memory");             \
                 __builtin_amdgcn_s_barrier();                                           \
                 __builtin_amdgcn_sched_barrier(0); }

    STAGE(0, 0);
    STAGE(1, 1);

    #pragma unroll 1
    for (int i = 0; i < 10; ++i) {
        const int t0 = i * 3;
        WAITV4; STAGE(2, t0 + 2); COMPUTE(0);
        WAITV4; STAGE(0, t0 + 3); COMPUTE(1);
        WAITV4; STAGE(1, t0 + 4); COMPUTE(2);
    }
    WAITV4; COMPUTE(0);
    WAITV0; COMPUTE(1);

#undef STAGE
#undef COMPUTE
#undef WAITV4
#undef WAITV0

    #pragma unroll
    for (int m = 0; m < 4; ++m) {
        #pragma unroll
        for (int n = 0; n < 4; ++n) {
            const int col = bn + wc + n * 16 + ln_c;
            const float bcol = bias[col];
            #pragma unroll
            for (int j = 0; j < 4; ++j) {
                const int row = bm + wr + m * 16 + ln_g * 4 + j;
                Fo[(size_t)row * D_ + col] = acc[m][n][j] + bcol;
            }
        }
    }
}

// ---------------------------------------------------------------- causal flash attention v4b
// (frozen from R10/R13: swapped-operand QK^T, register-direct PV, shuffle-free path)
__global__ __launch_bounds__(256, 4)
void attn_kernel(const bf16* __restrict__ Q, const bf16* __restrict__ K,
                 const bf16* __restrict__ Vt, bf16* __restrict__ ctx) {
    const int bh = blockIdx.x & 63;
    const int qt = 31 - (blockIdx.x >> 6);   // longest blocks dispatched first
    const int tid  = threadIdx.x;
    const int wave = tid >> 6;
    const int lane = tid & 63;
    const int ln_g = lane >> 4;
    const int ln_c = lane & 15;

    const bf16* Qp = Q  + (size_t)bh * T_ * HD_;
    const bf16* Kp = K  + (size_t)bh * T_ * HD_;
    const bf16* Vp = Vt + (size_t)bh * HD_ * T_;

    __shared__ bf16 Ks[64][72];
    __shared__ bf16 Vs[64][72];

    const int srow = tid >> 3;
    const int sc8  = (tid & 7) * 8;

    const int b = bh >> 4, h = bh & 15;

    const int qbase = qt * 64;
    const int qglob = qbase + wave * 16 + ln_c;

    const bf16x8 qf0 = *reinterpret_cast<const bf16x8*>(&Qp[(size_t)qglob * HD_ + ln_g * 8]);
    const bf16x8 qf1 = *reinterpret_cast<const bf16x8*>(&Qp[(size_t)qglob * HD_ + 32 + ln_g * 8]);

    f32x4 o[4] = {};
    float m = -INFINITY, l = 0.f;

    const int nk = qt + 1;

    int4 kr0, kr1, vr0, vr1;
    kr0 = *reinterpret_cast<const int4*>(&Kp[(size_t)srow * HD_ + sc8]);
    kr1 = *reinterpret_cast<const int4*>(&Kp[(size_t)(srow + 32) * HD_ + sc8]);
    vr0 = *reinterpret_cast<const int4*>(&Vp[(size_t)srow * T_ + sc8]);
    vr1 = *reinterpret_cast<const int4*>(&Vp[(size_t)(srow + 32) * T_ + sc8]);
    *reinterpret_cast<int4*>(&Ks[srow][sc8])      = kr0;
    *reinterpret_cast<int4*>(&Ks[srow + 32][sc8]) = kr1;
    *reinterpret_cast<int4*>(&Vs[srow][sc8])      = vr0;
    *reinterpret_cast<int4*>(&Vs[srow + 32][sc8]) = vr1;
    __syncthreads();

    for (int it = 0; it < nk; ++it) {
        const int kb = it * 64;
        const bool notlast = (it + 1 < nk);
        if (notlast) {
            const int kn = kb + 64;
            kr0 = *reinterpret_cast<const int4*>(&Kp[(size_t)(kn + srow) * HD_ + sc8]);
            kr1 = *reinterpret_cast<const int4*>(&Kp[(size_t)(kn + srow + 32) * HD_ + sc8]);
            vr0 = *reinterpret_cast<const int4*>(&Vp[(size_t)srow * T_ + kn + sc8]);
            vr1 = *reinterpret_cast<const int4*>(&Vp[(size_t)(srow + 32) * T_ + kn + sc8]);
        }

        f32x4 st[4];
        __builtin_amdgcn_s_setprio(1);
        #pragma unroll
        for (int kk = 0; kk < 4; ++kk) {
            bf16x8 kfa = *reinterpret_cast<const bf16x8*>(&Ks[kk * 16 + ln_c][ln_g * 8]);
            bf16x8 kfb = *reinterpret_cast<const bf16x8*>(&Ks[kk * 16 + ln_c][32 + ln_g * 8]);
            f32x4 z = {0.f, 0.f, 0.f, 0.f};
            z = __builtin_amdgcn_mfma_f32_16x16x32_bf16(kfa, qf0, z, 0, 0, 0);
            z = __builtin_amdgcn_mfma_f32_16x16x32_bf16(kfb, qf1, z, 0, 0, 0);
            st[kk] = z;
        }
        __builtin_amdgcn_s_setprio(0);

        if (!notlast) {
            #pragma unroll
            for (int kk = 0; kk < 4; ++kk)
                #pragma unroll
                for (int j = 0; j < 4; ++j)
                    if (kb + kk * 16 + ln_g * 4 + j > qglob) st[kk][j] = -INFINITY;
        }

        float mx = -INFINITY;
        #pragma unroll
        for (int kk = 0; kk < 4; ++kk)
            #pragma unroll
            for (int j = 0; j < 4; ++j)
                mx = fmaxf(mx, st[kk][j]);
        if (!__all(mx - m <= 8.f)) {
            float r = fmaxf(mx, __shfl_xor(mx, 16));
            r = fmaxf(r, __shfl_xor(r, 32));
            const float mnew = fmaxf(m, r);
            const float alpha = exp2f(m - mnew);
            l *= alpha;
            #pragma unroll
            for (int dt = 0; dt < 4; ++dt)
                #pragma unroll
                for (int j = 0; j < 4; ++j)
                    o[dt][j] *= alpha;
            m = mnew;
        }

        #pragma unroll
        for (int kk = 0; kk < 4; ++kk) {
            float p0 = exp2f(st[kk][0] - m);
            float p1 = exp2f(st[kk][1] - m);
            float p2 = exp2f(st[kk][2] - m);
            float p3 = exp2f(st[kk][3] - m);
            l += (p0 + p1) + (p2 + p3);
            uint2 pw;
            pw.x = bfbits(p0) | (bfbits(p1) << 16);
            pw.y = bfbits(p2) | (bfbits(p3) << 16);
            const s16x4 ps = __builtin_bit_cast(s16x4, pw);
            __builtin_amdgcn_s_setprio(1);
            #pragma unroll
            for (int dt = 0; dt < 4; ++dt) {
                s16x4 vf = *reinterpret_cast<const s16x4*>(
                    &Vs[dt * 16 + ln_c][kk * 16 + ln_g * 4]);
                o[dt] = mfma16(vf, ps, o[dt]);
            }
            __builtin_amdgcn_s_setprio(0);
        }

        if (notlast) {
            __syncthreads();
            *reinterpret_cast<int4*>(&Ks[srow][sc8])      = kr0;
            *reinterpret_cast<int4*>(&Ks[srow + 32][sc8]) = kr1;
            *reinterpret_cast<int4*>(&Vs[srow][sc8])      = vr0;
            *reinterpret_cast<int4*>(&Vs[srow + 32][sc8]) = vr1;
            __syncthreads();
        }
    }

    l += __shfl_xor(l, 16);
    l += __shfl_xor(l, 32);
    const float inv = 1.0f / l;
    bf16* dst = ctx + ((size_t)(b * T_ + qglob)) * D_ + h * HD_;
    #pragma unroll
    for (int dt = 0; dt < 4; ++dt) {
        union { bf16 hh[4]; uint2 u; } ok;
        #pragma unroll
        for (int j = 0; j < 4; ++j)
            ok.hh[j] = __float2bfloat16(o[dt][j] * inv);
        *reinterpret_cast<uint2*>(&dst[dt * 16 + ln_g * 4]) = ok.u;
    }
}

// ---------------------------------------------------------------- launch
extern "C" void kernel_launch(void* const* d_in, const int* in_sizes, int n_in,
                              void* d_out, int out_size, void* d_ws, size_t ws_size,
                              hipStream_t stream) {
    const float* x      = (const float*)d_in[0];
    const float* W_attn = (const float*)d_in[1];
    const float* b_attn = (const float*)d_in[2];
    const float* W_proj = (const float*)d_in[3];
    const float* b_proj = (const float*)d_in[4];
    float* out = (float*)d_out;

    char* ws = (char*)d_ws;
    bf16* xh  = (bf16*)ws;  ws += (size_t)BT_ * D_ * 2;
    bf16* WaT = (bf16*)ws;  ws += (size_t)3 * D_ * D_ * 2;
    bf16* WpT = (bf16*)ws;  ws += (size_t)D_ * D_ * 2;
    bf16* Qb  = (bf16*)ws;  ws += (size_t)BH_ * T_ * HD_ * 2;
    bf16* Kb  = (bf16*)ws;  ws += (size_t)BH_ * T_ * HD_ * 2;
    bf16* Vb  = (bf16*)ws;  ws += (size_t)BH_ * T_ * HD_ * 2;
    bf16* ctx = (bf16*)ws;  ws += (size_t)BT_ * D_ * 2;

    cast_kernel<<<(BT_ * D_ / 4 + 255) / 256, 256, 0, stream>>>(x, xh, BT_ * D_ / 4);
    transpose_cast<<<dim3(3 * D_ / 32, D_ / 32), dim3(32, 8), 0, stream>>>(W_attn, WaT, D_, 3 * D_);
    transpose_cast<<<dim3(D_ / 32, D_ / 32), dim3(32, 8), 0, stream>>>(W_proj, WpT, D_, D_);

    // QKV: 256^2 tile -> 32 x 12 = 384 blocks, 96 KB dynamic LDS
    gemm_qkv256<<<dim3(32, 12), 512, 98304, stream>>>(xh, WaT, b_attn, Qb, Kb, Vb);

    attn_kernel<<<dim3(BH_ * 32), 256, 0, stream>>>(Qb, Kb, Vb, ctx);

    // proj: 128^2 ring-3 (512 blocks = exactly 2/CU)
    gemm_proj<<<dim3(64, 8), 256, 0, stream>>>(ctx, WpT, b_proj, out);
}

// Round 17
// 180.107 us; speedup vs baseline: 1.4126x; 1.0739x over previous
//
#include <hip/hip_runtime.h>
#include <hip/hip_bf16.h>

using bf16 = __hip_bfloat16;
typedef __attribute__((ext_vector_type(8))) __bf16 bf16x8;
typedef __attribute__((ext_vector_type(4))) short s16x4;
typedef __attribute__((ext_vector_type(4))) float f32x4;

#define B_   4
#define T_   2048
#define D_   1024
#define H_   16
#define HD_  64
#define BH_  (B_ * H_)
#define BT_  (B_ * T_)

// Q pre-scale: 1/sqrt(64) * log2(e)  -> softmax computed with exp2
#define QSCALE 0.18033688011112042f

// async global->LDS DMA, 16B per lane; LDS dest is wave-uniform base + lane*16
__device__ __forceinline__ void gld_lds16(const void* g, void* l) {
    __builtin_amdgcn_global_load_lds(
        (const __attribute__((address_space(1))) unsigned int*)g,
        (__attribute__((address_space(3))) unsigned int*)l,
        16, 0, 0);
}

// 16x16x16 bf16 MFMA (B-frag k = (lane>>4)*4 + j == QK^T C-frag layout).
__device__ __forceinline__ f32x4 mfma16(s16x4 a, s16x4 b, f32x4 c) {
#if defined(__HIP_DEVICE_COMPILE__)
  #if __has_builtin(__builtin_amdgcn_mfma_f32_16x16x16bf16_1k)
    return __builtin_amdgcn_mfma_f32_16x16x16bf16_1k(a, b, c, 0, 0, 0);
  #else
    f32x4 d;
    asm volatile("v_mfma_f32_16x16x16_bf16 %0, %1, %2, %3\n\ts_nop 7\n\ts_nop 7"
                 : "=v"(d) : "v"(a), "v"(b), "v"(c));
    return d;
  #endif
#else
    (void)a; (void)b;
    return c;
#endif
}

__device__ __forceinline__ unsigned bfbits(float x) {
    return (unsigned)__builtin_bit_cast(unsigned short, __float2bfloat16(x));
}

// ---------------------------------------------------------------- fused prep
// One launch: [0,4096) cast x -> bf16 (8 elems/thread, 16B stores);
// [4096,7168) transpose+cast W_attn (3072 32x32 tiles);
// [7168,8192) transpose+cast W_proj (1024 tiles).
__global__ __launch_bounds__(256)
void prep_kernel(const float* __restrict__ x,
                 const float* __restrict__ W_attn,
                 const float* __restrict__ W_proj,
                 bf16* __restrict__ xh, bf16* __restrict__ WaT, bf16* __restrict__ WpT) {
    __shared__ float tile[32][33];
    const int blk = blockIdx.x;
    const int tid = threadIdx.x;

    if (blk < 4096) {                       // ---- cast: 8,388,608 elems = 4096*256*8
        const size_t i = ((size_t)blk * 256 + tid) * 8;
        float4 v0 = *reinterpret_cast<const float4*>(x + i);
        float4 v1 = *reinterpret_cast<const float4*>(x + i + 4);
        uint4 p;
        p.x = bfbits(v0.x) | (bfbits(v0.y) << 16);
        p.y = bfbits(v0.z) | (bfbits(v0.w) << 16);
        p.z = bfbits(v1.x) | (bfbits(v1.y) << 16);
        p.w = bfbits(v1.z) | (bfbits(v1.w) << 16);
        *reinterpret_cast<uint4*>(xh + i) = p;
        return;
    }

    const float* W;
    bf16* Wt;
    int nb, kb;
    if (blk < 4096 + 3072) {                // ---- W_attn [1024][3072] -> WaT [3072][1024]
        const int t = blk - 4096;
        W = W_attn; Wt = WaT;
        nb = (t % 96) * 32; kb = (t / 96) * 32;
        const int tx = tid & 31, ty = tid >> 5;
        #pragma unroll
        for (int i = 0; i < 32; i += 8)
            tile[ty + i][tx] = W[(size_t)(kb + ty + i) * 3072 + nb + tx];
        __syncthreads();
        #pragma unroll
        for (int i = 0; i < 32; i += 8)
            Wt[(size_t)(nb + ty + i) * 1024 + kb + tx] = __float2bfloat16(tile[tx][ty + i]);
    } else {                                // ---- W_proj [1024][1024] -> WpT
        const int t = blk - 4096 - 3072;
        W = W_proj; Wt = WpT;
        nb = (t % 32) * 32; kb = (t / 32) * 32;
        const int tx = tid & 31, ty = tid >> 5;
        #pragma unroll
        for (int i = 0; i < 32; i += 8)
            tile[ty + i][tx] = W[(size_t)(kb + ty + i) * 1024 + nb + tx];
        __syncthreads();
        #pragma unroll
        for (int i = 0; i < 32; i += 8)
            Wt[(size_t)(nb + ty + i) * 1024 + kb + tx] = __float2bfloat16(tile[tx][ty + i]);
    }
}

// ---------------------------------------------------------------- GEMM  C = A @ Bt^T (+bias)
// R13-verified: 128x128 tile, K=1024, BK=32, ring-3 LDS (48 KB), counted vmcnt
// (one 4-call stage in flight across each barrier), XOR-swizzled LDS (0-conflict).
// MODE 0: QKV scatter (Q*QSCALE, K, V^T). MODE 1: fp32 out + bias.
template <int MODE>
__global__ __launch_bounds__(256)
void gemm_bt(const bf16* __restrict__ A, const bf16* __restrict__ Bt,
             const float* __restrict__ bias,
             bf16* __restrict__ Qo, bf16* __restrict__ Ko, bf16* __restrict__ Vo,
             float* __restrict__ Fo) {
    constexpr int K = 1024;
    const int bm = blockIdx.x * 128;
    const int bn = blockIdx.y * 128;
    const int tid  = threadIdx.x;
    const int wid  = tid >> 6;
    const int lane = tid & 63;
    const int wr = (wid >> 1) * 64;
    const int wc = (wid & 1) * 64;
    const int ln_g = lane >> 4;    // 0..3
    const int ln_c = lane & 15;    // 0..15

    __shared__ bf16 sm[3][2][128][32];   // ring-3: [slot][A/B][row][col]

    f32x4 acc[4][4] = {};

    const int g_row0 = wid * 32 + (lane >> 2);
    const int g_chk  = ((lane & 3) ^ ((lane >> 3) & 3)) * 8;
    const int l_row0 = wid * 32;
    const int colx = (ln_g * 16) ^ (((ln_c >> 1) & 3) << 4);

#define STAGE(S_, T_) {                                                               \
    gld_lds16(&A [(size_t)(bm + g_row0)      * K + (T_) * 32 + g_chk], &sm[S_][0][l_row0][0]);      \
    gld_lds16(&A [(size_t)(bm + g_row0 + 16) * K + (T_) * 32 + g_chk], &sm[S_][0][l_row0 + 16][0]); \
    gld_lds16(&Bt[(size_t)(bn + g_row0)      * K + (T_) * 32 + g_chk], &sm[S_][1][l_row0][0]);      \
    gld_lds16(&Bt[(size_t)(bn + g_row0 + 16) * K + (T_) * 32 + g_chk], &sm[S_][1][l_row0 + 16][0]); }

#define COMPUTE(S_) {                                                                    \
    bf16x8 af[4], bfr[4];                                                                \
    _Pragma("unroll")                                                                    \
    for (int m = 0; m < 4; ++m)                                                          \
        af[m] = *reinterpret_cast<const bf16x8*>(                                        \
            (const char*)&sm[S_][0][wr + m * 16 + ln_c][0] + colx);                      \
    _Pragma("unroll")                                                                    \
    for (int n = 0; n < 4; ++n)                                                          \
        bfr[n] = *reinterpret_cast<const bf16x8*>(                                       \
            (const char*)&sm[S_][1][wc + n * 16 + ln_c][0] + colx);                      \
    _Pragma("unroll")                                                                    \
    for (int m = 0; m < 4; ++m)                                                          \
        _Pragma("unroll")                                                                \
        for (int n = 0; n < 4; ++n)                                                      \
            acc[m][n] = __builtin_amdgcn_mfma_f32_16x16x32_bf16(af[m], bfr[n],           \
                                                                 acc[m][n], 0, 0, 0); }

#define WAITV4 { asm volatile("s_waitcnt vmcnt(4) lgkmcnt(0)" ::: "memory");             \
                 __builtin_amdgcn_s_barrier();                                           \
                 __builtin_amdgcn_sched_barrier(0); }
#define WAITV0 { asm volatile("s_waitcnt vmcnt(0) lgkmcnt(0)" ::: "memory");             \
                 __builtin_amdgcn_s_barrier();                                           \
                 __builtin_amdgcn_sched_barrier(0); }

    STAGE(0, 0);
    STAGE(1, 1);

    #pragma unroll 1
    for (int i = 0; i < 10; ++i) {
        const int t0 = i * 3;
        WAITV4; STAGE(2, t0 + 2); COMPUTE(0);
        WAITV4; STAGE(0, t0 + 3); COMPUTE(1);
        WAITV4; STAGE(1, t0 + 4); COMPUTE(2);
    }
    WAITV4; COMPUTE(0);   // tile 30 (tile 31's stage in flight)
    WAITV0; COMPUTE(1);   // tile 31

#undef STAGE
#undef COMPUTE
#undef WAITV4
#undef WAITV0

    #pragma unroll
    for (int m = 0; m < 4; ++m) {
        #pragma unroll
        for (int n = 0; n < 4; ++n) {
            const int col = bn + wc + n * 16 + ln_c;
            const float bcol = bias[col];
            #pragma unroll
            for (int j = 0; j < 4; ++j) {
                const int row = bm + wr + m * 16 + ln_g * 4 + j;
                float v = acc[m][n][j] + bcol;
                if (MODE == 0) {
                    const int part = col >> 10;       // 0=q 1=k 2=v
                    const int cc = col & 1023;
                    const int h = cc >> 6, d = cc & 63;
                    const int b = row >> 11, t = row & 2047;
                    const int bh = b * H_ + h;
                    if (part == 0)
                        Qo[((size_t)bh * T_ + t) * HD_ + d] = __float2bfloat16(v * QSCALE);
                    else if (part == 1)
                        Ko[((size_t)bh * T_ + t) * HD_ + d] = __float2bfloat16(v);
                    else
                        Vo[((size_t)bh * HD_ + d) * T_ + t] = __float2bfloat16(v);
                } else {
                    Fo[(size_t)row * D_ + col] = v;
                }
            }
        }
    }
}

// ---------------------------------------------------------------- causal flash attention v4b
// (frozen: swapped-operand QK^T, register-direct PV via mfma16, shuffle-free path)
__global__ __launch_bounds__(256, 4)
void attn_kernel(const bf16* __restrict__ Q, const bf16* __restrict__ K,
                 const bf16* __restrict__ Vt, bf16* __restrict__ ctx) {
    const int bh = blockIdx.x & 63;
    const int qt = 31 - (blockIdx.x >> 6);   // longest blocks dispatched first
    const int tid  = threadIdx.x;
    const int wave = tid >> 6;
    const int lane = tid & 63;
    const int ln_g = lane >> 4;
    const int ln_c = lane & 15;

    const bf16* Qp = Q  + (size_t)bh * T_ * HD_;
    const bf16* Kp = K  + (size_t)bh * T_ * HD_;
    const bf16* Vp = Vt + (size_t)bh * HD_ * T_;

    __shared__ bf16 Ks[64][72];
    __shared__ bf16 Vs[64][72];

    const int srow = tid >> 3;
    const int sc8  = (tid & 7) * 8;

    const int b = bh >> 4, h = bh & 15;

    const int qbase = qt * 64;
    const int qglob = qbase + wave * 16 + ln_c;

    const bf16x8 qf0 = *reinterpret_cast<const bf16x8*>(&Qp[(size_t)qglob * HD_ + ln_g * 8]);
    const bf16x8 qf1 = *reinterpret_cast<const bf16x8*>(&Qp[(size_t)qglob * HD_ + 32 + ln_g * 8]);

    f32x4 o[4] = {};
    float m = -INFINITY, l = 0.f;

    const int nk = qt + 1;

    int4 kr0, kr1, vr0, vr1;
    kr0 = *reinterpret_cast<const int4*>(&Kp[(size_t)srow * HD_ + sc8]);
    kr1 = *reinterpret_cast<const int4*>(&Kp[(size_t)(srow + 32) * HD_ + sc8]);
    vr0 = *reinterpret_cast<const int4*>(&Vp[(size_t)srow * T_ + sc8]);
    vr1 = *reinterpret_cast<const int4*>(&Vp[(size_t)(srow + 32) * T_ + sc8]);
    *reinterpret_cast<int4*>(&Ks[srow][sc8])      = kr0;
    *reinterpret_cast<int4*>(&Ks[srow + 32][sc8]) = kr1;
    *reinterpret_cast<int4*>(&Vs[srow][sc8])      = vr0;
    *reinterpret_cast<int4*>(&Vs[srow + 32][sc8]) = vr1;
    __syncthreads();

    for (int it = 0; it < nk; ++it) {
        const int kb = it * 64;
        const bool notlast = (it + 1 < nk);
        if (notlast) {
            const int kn = kb + 64;
            kr0 = *reinterpret_cast<const int4*>(&Kp[(size_t)(kn + srow) * HD_ + sc8]);
            kr1 = *reinterpret_cast<const int4*>(&Kp[(size_t)(kn + srow + 32) * HD_ + sc8]);
            vr0 = *reinterpret_cast<const int4*>(&Vp[(size_t)srow * T_ + kn + sc8]);
            vr1 = *reinterpret_cast<const int4*>(&Vp[(size_t)(srow + 32) * T_ + kn + sc8]);
        }

        f32x4 st[4];
        __builtin_amdgcn_s_setprio(1);
        #pragma unroll
        for (int kk = 0; kk < 4; ++kk) {
            bf16x8 kfa = *reinterpret_cast<const bf16x8*>(&Ks[kk * 16 + ln_c][ln_g * 8]);
            bf16x8 kfb = *reinterpret_cast<const bf16x8*>(&Ks[kk * 16 + ln_c][32 + ln_g * 8]);
            f32x4 z = {0.f, 0.f, 0.f, 0.f};
            z = __builtin_amdgcn_mfma_f32_16x16x32_bf16(kfa, qf0, z, 0, 0, 0);
            z = __builtin_amdgcn_mfma_f32_16x16x32_bf16(kfb, qf1, z, 0, 0, 0);
            st[kk] = z;
        }
        __builtin_amdgcn_s_setprio(0);

        if (!notlast) {
            #pragma unroll
            for (int kk = 0; kk < 4; ++kk)
                #pragma unroll
                for (int j = 0; j < 4; ++j)
                    if (kb + kk * 16 + ln_g * 4 + j > qglob) st[kk][j] = -INFINITY;
        }

        float mx = -INFINITY;
        #pragma unroll
        for (int kk = 0; kk < 4; ++kk)
            #pragma unroll
            for (int j = 0; j < 4; ++j)
                mx = fmaxf(mx, st[kk][j]);
        if (!__all(mx - m <= 8.f)) {
            float r = fmaxf(mx, __shfl_xor(mx, 16));
            r = fmaxf(r, __shfl_xor(r, 32));
            const float mnew = fmaxf(m, r);
            const float alpha = exp2f(m - mnew);
            l *= alpha;
            #pragma unroll
            for (int dt = 0; dt < 4; ++dt)
                #pragma unroll
                for (int j = 0; j < 4; ++j)
                    o[dt][j] *= alpha;
            m = mnew;
        }

        #pragma unroll
        for (int kk = 0; kk < 4; ++kk) {
            float p0 = exp2f(st[kk][0] - m);
            float p1 = exp2f(st[kk][1] - m);
            float p2 = exp2f(st[kk][2] - m);
            float p3 = exp2f(st[kk][3] - m);
            l += (p0 + p1) + (p2 + p3);
            uint2 pw;
            pw.x = bfbits(p0) | (bfbits(p1) << 16);
            pw.y = bfbits(p2) | (bfbits(p3) << 16);
            const s16x4 ps = __builtin_bit_cast(s16x4, pw);
            __builtin_amdgcn_s_setprio(1);
            #pragma unroll
            for (int dt = 0; dt < 4; ++dt) {
                s16x4 vf = *reinterpret_cast<const s16x4*>(
                    &Vs[dt * 16 + ln_c][kk * 16 + ln_g * 4]);
                o[dt] = mfma16(vf, ps, o[dt]);
            }
            __builtin_amdgcn_s_setprio(0);
        }

        if (notlast) {
            __syncthreads();
            *reinterpret_cast<int4*>(&Ks[srow][sc8])      = kr0;
            *reinterpret_cast<int4*>(&Ks[srow + 32][sc8]) = kr1;
            *reinterpret_cast<int4*>(&Vs[srow][sc8])      = vr0;
            *reinterpret_cast<int4*>(&Vs[srow + 32][sc8]) = vr1;
            __syncthreads();
        }
    }

    l += __shfl_xor(l, 16);
    l += __shfl_xor(l, 32);
    const float inv = 1.0f / l;
    bf16* dst = ctx + ((size_t)(b * T_ + qglob)) * D_ + h * HD_;
    #pragma unroll
    for (int dt = 0; dt < 4; ++dt) {
        union { bf16 hh[4]; uint2 u; } ok;
        #pragma unroll
        for (int j = 0; j < 4; ++j)
            ok.hh[j] = __float2bfloat16(o[dt][j] * inv);
        *reinterpret_cast<uint2*>(&dst[dt * 16 + ln_g * 4]) = ok.u;
    }
}

// ---------------------------------------------------------------- launch
extern "C" void kernel_launch(void* const* d_in, const int* in_sizes, int n_in,
                              void* d_out, int out_size, void* d_ws, size_t ws_size,
                              hipStream_t stream) {
    const float* x      = (const float*)d_in[0];
    const float* W_attn = (const float*)d_in[1];
    const float* b_attn = (const float*)d_in[2];
    const float* W_proj = (const float*)d_in[3];
    const float* b_proj = (const float*)d_in[4];
    float* out = (float*)d_out;

    char* ws = (char*)d_ws;
    bf16* xh  = (bf16*)ws;  ws += (size_t)BT_ * D_ * 2;
    bf16* WaT = (bf16*)ws;  ws += (size_t)3 * D_ * D_ * 2;
    bf16* WpT = (bf16*)ws;  ws += (size_t)D_ * D_ * 2;
    bf16* Qb  = (bf16*)ws;  ws += (size_t)BH_ * T_ * HD_ * 2;
    bf16* Kb  = (bf16*)ws;  ws += (size_t)BH_ * T_ * HD_ * 2;
    bf16* Vb  = (bf16*)ws;  ws += (size_t)BH_ * T_ * HD_ * 2;
    bf16* ctx = (bf16*)ws;  ws += (size_t)BT_ * D_ * 2;

    // fused prep: cast (4096 blocks) + W_attn^T (3072) + W_proj^T (1024)
    prep_kernel<<<8192, 256, 0, stream>>>(x, W_attn, W_proj, xh, WaT, WpT);

    gemm_bt<0><<<dim3(BT_ / 128, 3 * D_ / 128), 256, 0, stream>>>(
        xh, WaT, b_attn, Qb, Kb, Vb, nullptr);

    attn_kernel<<<dim3(BH_ * 32), 256, 0, stream>>>(Qb, Kb, Vb, ctx);

    gemm_bt<1><<<dim3(BT_ / 128, D_ / 128), 256, 0, stream>>>(
        ctx, WpT, b_proj, nullptr, nullptr, nullptr, out);
}